// Round 7
// baseline (401.318 us; speedup 1.0000x reference)
//
#include <hip/hip_runtime.h>
#include <cstdint>

// ---------------------------------------------------------------------------
// Attention (Luong general): out = softmax(dec @ (enc@W)^T) @ enc
// B=8, S_enc=S_dec=2048, H=512, fp32 in/out.
//
// Round 7 = round 5 (passing, 370us) + two isolated deltas:
//  * encprep: fused enc split + bf16 transpose (one read of enc).
//  * enc_proj moved to gemm_bt32 (32x32x16 MFMA) as a LAYOUT PROBE: if the
//    32x32 A/B//C/D mappings are wrong this shows up as large-FINITE absmax
//    (never NaN -- no stats path here), cleanly diagnosable.
// Logits gemm (16x16x32 + stats) and pv_wide are r5-verified verbatim.
// ---------------------------------------------------------------------------

#define DEVINL __device__ __forceinline__

typedef __attribute__((ext_vector_type(8)))  short short8;
typedef __attribute__((ext_vector_type(4)))  short short4v;
typedef __attribute__((ext_vector_type(4)))  float f32x4;
typedef __attribute__((ext_vector_type(16))) float f32x16;

DEVINL short f2bf(float x) {
    union { float f; uint32_t u; } v; v.f = x;
    uint32_t r = v.u + 0x7FFFu + ((v.u >> 16) & 1u);   // RNE
    return (short)(r >> 16);
}
DEVINL float bf2f(short h) {
    union { uint32_t u; float f; } v; v.u = ((uint32_t)(uint16_t)h) << 16;
    return v.f;
}

DEVINL void gload_lds16(const void* g, void* l) {
    __builtin_amdgcn_global_load_lds(
        (const __attribute__((address_space(1))) char*)g,
        (__attribute__((address_space(3))) char*)l, 16, 0, 0);
}

// ---------------------------------------------------------------------------
// split fp32 -> (hi, lo) bf16 arrays (dec).
// ---------------------------------------------------------------------------
__global__ __launch_bounds__(256)
void split_kernel(const float* __restrict__ x, short* __restrict__ hi,
                  short* __restrict__ lo)
{
    long i = ((long)blockIdx.x * 256 + threadIdx.x) * 8;
    f32x4 a = *(const f32x4*)(x + i);
    f32x4 b = *(const f32x4*)(x + i + 4);
    short8 h, l;
#pragma unroll
    for (int j = 0; j < 4; j++) {
        short ha = f2bf(a[j]); h[j] = ha;     l[j] = f2bf(a[j] - bf2f(ha));
        short hb = f2bf(b[j]); h[4 + j] = hb; l[4 + j] = f2bf(b[j] - bf2f(hb));
    }
    *(short8*)(hi + i) = h;
    *(short8*)(lo + i) = l;
}

// W[512k][512n] -> Wt_hi/lo[n][k]
__global__ __launch_bounds__(256)
void split_w_kernel(const float* __restrict__ w, short* __restrict__ wth,
                    short* __restrict__ wtl)
{
    int idx = blockIdx.x * 256 + threadIdx.x;   // k*512 + n
    int k = idx >> 9, n = idx & 511;
    float v = w[idx];
    short h = f2bf(v);
    wth[(long)n * 512 + k] = h;
    wtl[(long)n * 512 + k] = f2bf(v - bf2f(h));
}

// fused: enc fp32 -> enc_hi, enc_lo (row-major) + enc_t (bf16 transposed)
__global__ __launch_bounds__(256)
void encprep_kernel(const float* __restrict__ enc, short* __restrict__ hi,
                    short* __restrict__ lo, short* __restrict__ xt)
{
    __shared__ short tile[32][33];
    const int b  = blockIdx.z;
    const int s0 = blockIdx.x * 32;
    const int e0 = blockIdx.y * 32;
    short* pt = xt + (long)b * 512 * 2048;
    const int tx = threadIdx.x & 31;
    const int ty = threadIdx.x >> 5;   // 0..7
#pragma unroll
    for (int r = 0; r < 32; r += 8) {
        long idx = (long)b * 2048 * 512 + (long)(s0 + ty + r) * 512 + e0 + tx;
        float v = enc[idx];
        short h = f2bf(v);
        hi[idx] = h;
        lo[idx] = f2bf(v - bf2f(h));
        tile[ty + r][tx] = h;
    }
    __syncthreads();
#pragma unroll
    for (int r = 0; r < 32; r += 8)
        pt[(long)(e0 + ty + r) * 2048 + s0 + tx] = tile[tx][ty + r];
}

// ---------------------------------------------------------------------------
// gemm_bt: r5-verified 16x16x32 path.  C[m][n] = sum_k A[m][k]*B[n][k].
// 128x128 tile, BK=32, 4 waves, dbuf LDS, NTERMS=3 split precision.
// STATS: per-(row, n-tile) softmax partials.
// ---------------------------------------------------------------------------
template<int NTERMS, bool SPLIT_OUT, bool STATS>
__global__ __launch_bounds__(256, 2)
void gemm_bt(const short* __restrict__ Ah, const short* __restrict__ Al,
             const short* __restrict__ Bh, const short* __restrict__ Bl,
             float* __restrict__ C, short* __restrict__ Ch, short* __restrict__ Cl,
             float2* __restrict__ stats,
             int K, int lda, int ldb, int ldc,
             long sA, long sB, long sC)
{
    extern __shared__ char smem_raw[];
    constexpr int OPS = (NTERMS == 3) ? 4 : 2;
    constexpr int SET = 128 * 32 * OPS;
    short* smem = (short*)smem_raw;

    const int tid  = threadIdx.x;
    const int wave = tid >> 6;
    const int lane = tid & 63;
    const int quad = lane >> 4;
    const int l16  = lane & 15;
    const int wm   = (wave >> 1) * 64;
    const int wn   = (wave & 1) * 64;

    const long tile_m = (long)blockIdx.y * 128;
    const long tile_n = (long)blockIdx.x * 128;
    const int  bz     = blockIdx.z;

    const short* pAh = Ah + (long)bz * sA;
    const short* pBh = Bh + (long)bz * sB;
    const short* pAl = (NTERMS == 3) ? (Al + (long)bz * sA) : nullptr;
    const short* pBl = (NTERMS == 3) ? (Bl + (long)bz * sB) : nullptr;

    const int srow = tid >> 2;
    const int skq  = (tid & 3) * 8;
    const int lds_off = srow * 32 + skq;
    const long ga0 = (tile_m + srow) * (long)lda + skq;
    const long gb0 = (tile_n + srow) * (long)ldb + skq;

    auto stage = [&](int k0, int buf) {
        short* s   = smem + buf * SET;
        short* ash = s;
        short* bsh = s + 128 * 32;
        gload_lds16(pAh + ga0 + k0,             ash + lds_off);
        gload_lds16(pAh + ga0 + 64l * lda + k0, ash + lds_off + 64 * 32);
        gload_lds16(pBh + gb0 + k0,             bsh + lds_off);
        gload_lds16(pBh + gb0 + 64l * ldb + k0, bsh + lds_off + 64 * 32);
        if constexpr (NTERMS == 3) {
            short* asl = s + 2 * 128 * 32;
            short* bsl = s + 3 * 128 * 32;
            gload_lds16(pAl + ga0 + k0,             asl + lds_off);
            gload_lds16(pAl + ga0 + 64l * lda + k0, asl + lds_off + 64 * 32);
            gload_lds16(pBl + gb0 + k0,             bsl + lds_off);
            gload_lds16(pBl + gb0 + 64l * ldb + k0, bsl + lds_off + 64 * 32);
        }
    };

    f32x4 acc[4][4] = {};
    stage(0, 0);
    int cur = 0;

    for (int k0 = 0; k0 < K; k0 += 32) {
        __syncthreads();
        if (k0 + 32 < K) stage(k0 + 32, cur ^ 1);

        short* s   = smem + cur * SET;
        short* ash = s;
        short* bsh = s + 128 * 32;
        short* asl = s + 2 * 128 * 32;
        short* bsl = s + 3 * 128 * 32;

        short8 ah[4], bh[4], al[4], bl[4];
#pragma unroll
        for (int i = 0; i < 4; i++) {
            ah[i] = *(const short8*)&ash[(wm + i * 16 + l16) * 32 + quad * 8];
            bh[i] = *(const short8*)&bsh[(wn + i * 16 + l16) * 32 + quad * 8];
            if constexpr (NTERMS == 3) {
                al[i] = *(const short8*)&asl[(wm + i * 16 + l16) * 32 + quad * 8];
                bl[i] = *(const short8*)&bsl[(wn + i * 16 + l16) * 32 + quad * 8];
            }
        }
#pragma unroll
        for (int i = 0; i < 4; i++)
#pragma unroll
            for (int j = 0; j < 4; j++) {
                acc[i][j] = __builtin_amdgcn_mfma_f32_16x16x32_bf16(ah[i], bh[j], acc[i][j], 0, 0, 0);
                if constexpr (NTERMS == 3) {
                    acc[i][j] = __builtin_amdgcn_mfma_f32_16x16x32_bf16(ah[i], bl[j], acc[i][j], 0, 0, 0);
                    acc[i][j] = __builtin_amdgcn_mfma_f32_16x16x32_bf16(al[i], bh[j], acc[i][j], 0, 0, 0);
                }
            }
        cur ^= 1;
    }

    if constexpr (STATS) {
        float* sred = (float*)(smem + 2 * SET);
        float mrow[4][4], lrow[4][4];
#pragma unroll
        for (int i = 0; i < 4; i++)
#pragma unroll
            for (int r = 0; r < 4; r++) {
                float m = acc[i][0][r];
#pragma unroll
                for (int j = 1; j < 4; j++) m = fmaxf(m, acc[i][j][r]);
                m = fmaxf(m, __shfl_xor(m, 1));
                m = fmaxf(m, __shfl_xor(m, 2));
                m = fmaxf(m, __shfl_xor(m, 4));
                m = fmaxf(m, __shfl_xor(m, 8));
                mrow[i][r] = m;
            }
        __syncthreads();
        if (l16 == 0) {
#pragma unroll
            for (int i = 0; i < 4; i++)
#pragma unroll
                for (int r = 0; r < 4; r++)
                    sred[(wm + i * 16 + quad * 4 + r) * 2 + (wave & 1)] = mrow[i][r];
        }
        __syncthreads();
#pragma unroll
        for (int i = 0; i < 4; i++)
#pragma unroll
            for (int r = 0; r < 4; r++) {
                int row = wm + i * 16 + quad * 4 + r;
                mrow[i][r] = fmaxf(sred[row * 2], sred[row * 2 + 1]);
            }
        __syncthreads();
#pragma unroll
        for (int i = 0; i < 4; i++)
#pragma unroll
            for (int r = 0; r < 4; r++) {
                float s = 0.f;
#pragma unroll
                for (int j = 0; j < 4; j++) s += __expf(acc[i][j][r] - mrow[i][r]);
                s += __shfl_xor(s, 1);
                s += __shfl_xor(s, 2);
                s += __shfl_xor(s, 4);
                s += __shfl_xor(s, 8);
                lrow[i][r] = s;
            }
        if (l16 == 0) {
#pragma unroll
            for (int i = 0; i < 4; i++)
#pragma unroll
                for (int r = 0; r < 4; r++)
                    sred[(wm + i * 16 + quad * 4 + r) * 2 + (wave & 1)] = lrow[i][r];
        }
        __syncthreads();
        if ((wave & 1) == 0 && l16 == 0) {
#pragma unroll
            for (int i = 0; i < 4; i++)
#pragma unroll
                for (int r = 0; r < 4; r++) {
                    int row = wm + i * 16 + quad * 4 + r;
                    long grow = tile_m + row;
                    float2 v; v.x = mrow[i][r];
                    v.y = sred[row * 2] + sred[row * 2 + 1];
                    stats[((long)bz * 2048 + grow) * 16 + blockIdx.x] = v;
                }
        }
    }

#pragma unroll
    for (int i = 0; i < 4; i++)
#pragma unroll
        for (int j = 0; j < 4; j++) {
            const long row0 = tile_m + wm + i * 16 + quad * 4;
            const long col  = tile_n + wn + j * 16 + l16;
#pragma unroll
            for (int r = 0; r < 4; r++) {
                float v = acc[i][j][r];
                if constexpr (SPLIT_OUT) {
                    long idx = (long)bz * sC + (row0 + r) * (long)ldc + col;
                    short h = f2bf(v);
                    Ch[idx] = h;
                    Cl[idx] = f2bf(v - bf2f(h));
                } else {
                    C[(long)bz * sC + (row0 + r) * (long)ldc + col] = v;
                }
            }
        }
}

// ---------------------------------------------------------------------------
// gemm_bt32: 32x32x16 MFMA probe (enc_proj only; no stats -> NaN-impossible,
// mapping errors show as large-finite absmax).  128x128 tile, BK=16, dbuf.
// A/B frag guess: row = lane&31, k = (lane>>5)*8 + elem (analog of verified
// 16x16x32).  C/D (m74/m101-verified): col=lane&31,
// row=(reg&3)+8*(reg>>2)+4*(lane>>5).
// ---------------------------------------------------------------------------
__global__ __launch_bounds__(256, 2)
void gemm_bt32_split(const short* __restrict__ Ah, const short* __restrict__ Al,
                     const short* __restrict__ Bh, const short* __restrict__ Bl,
                     short* __restrict__ Ch, short* __restrict__ Cl,
                     int K, int lda, int ldb, int ldc)
{
    extern __shared__ char smem_raw[];
    constexpr int PL  = 128 * 16;
    constexpr int SET = PL * 4;
    short* smem = (short*)smem_raw;

    const int tid   = threadIdx.x;
    const int wave  = tid >> 6;
    const int lane  = tid & 63;
    const int l32   = lane & 31;
    const int khalf = lane >> 5;
    const int wm    = (wave >> 1) * 64;
    const int wn    = (wave & 1) * 64;

    const long tile_m = (long)blockIdx.y * 128;
    const long tile_n = (long)blockIdx.x * 128;

    const int srow = tid >> 1;
    const int skq  = (tid & 1) * 8;
    const int lds_off = srow * 16 + skq;
    const long ga0 = (tile_m + srow) * (long)lda + skq;
    const long gb0 = (tile_n + srow) * (long)ldb + skq;

    auto stage = [&](int k0, int buf) {
        short* s = smem + buf * SET;
        gload_lds16(Ah + ga0 + k0, s + lds_off);
        gload_lds16(Bh + gb0 + k0, s + PL + lds_off);
        gload_lds16(Al + ga0 + k0, s + 2 * PL + lds_off);
        gload_lds16(Bl + gb0 + k0, s + 3 * PL + lds_off);
    };

    f32x16 acc[2][2] = {};
    stage(0, 0);
    int cur = 0;

    for (int k0 = 0; k0 < K; k0 += 16) {
        __syncthreads();
        if (k0 + 16 < K) stage(k0 + 16, cur ^ 1);

        short* s = smem + cur * SET;
        short8 ah[2], bh[2], al[2], bl[2];
#pragma unroll
        for (int i = 0; i < 2; i++) {
            ah[i] = *(const short8*)&s[(wm + i * 32 + l32) * 16 + khalf * 8];
            bh[i] = *(const short8*)&s[PL + (wn + i * 32 + l32) * 16 + khalf * 8];
            al[i] = *(const short8*)&s[2 * PL + (wm + i * 32 + l32) * 16 + khalf * 8];
            bl[i] = *(const short8*)&s[3 * PL + (wn + i * 32 + l32) * 16 + khalf * 8];
        }
#pragma unroll
        for (int i = 0; i < 2; i++)
#pragma unroll
            for (int j = 0; j < 2; j++) {
                acc[i][j] = __builtin_amdgcn_mfma_f32_32x32x16_bf16(ah[i], bh[j], acc[i][j], 0, 0, 0);
                acc[i][j] = __builtin_amdgcn_mfma_f32_32x32x16_bf16(ah[i], bl[j], acc[i][j], 0, 0, 0);
                acc[i][j] = __builtin_amdgcn_mfma_f32_32x32x16_bf16(al[i], bh[j], acc[i][j], 0, 0, 0);
            }
        cur ^= 1;
    }

#pragma unroll
    for (int i = 0; i < 2; i++)
#pragma unroll
        for (int j = 0; j < 2; j++) {
            const long colg = tile_n + wn + j * 32 + l32;
#pragma unroll
            for (int r = 0; r < 16; r++) {
                const long rowg = tile_m + wm + i * 32 + (r & 3) + 8 * (r >> 2) + 4 * khalf;
                float v = acc[i][j][r];
                long idx = rowg * (long)ldc + colg;
                short h = f2bf(v);
                Ch[idx] = h;
                Cl[idx] = f2bf(v - bf2f(h));
            }
        }
}

// ---------------------------------------------------------------------------
// combine: per row, fold 16 tile partials -> (max, 1/sum)
// ---------------------------------------------------------------------------
__global__ __launch_bounds__(256)
void combine_kernel(const float2* __restrict__ stats, float* __restrict__ Mrow,
                    float* __restrict__ Linv)
{
    long r = (long)blockIdx.x * 256 + threadIdx.x;
    const float2* s = stats + r * 16;
    float2 v[16];
#pragma unroll
    for (int i = 0; i < 16; i++) v[i] = s[i];
    float m = v[0].x;
#pragma unroll
    for (int i = 1; i < 16; i++) m = fmaxf(m, v[i].x);
    float l = 0.f;
#pragma unroll
    for (int i = 0; i < 16; i++) l += v[i].y * __expf(v[i].x - m);
    Mrow[r] = m;
    Linv[r] = 1.f / l;
}

// ---------------------------------------------------------------------------
// pv_wide: r5-verified verbatim.  64 q x 512 e, 8 waves, grid (32, 8).
// ---------------------------------------------------------------------------
__global__ __launch_bounds__(512, 2)
void pv_wide(const float* __restrict__ S, const short* __restrict__ encT,
             const float* __restrict__ Mrow, const float* __restrict__ Linv,
             float* __restrict__ Out)
{
    extern __shared__ char smem_raw[];
    short* As = (short*)smem_raw;

    const int tid  = threadIdx.x;
    const int wave = tid >> 6;
    const int lane = tid & 63;
    const int quad = lane >> 4;
    const int l16  = lane & 15;

    const int  bz     = blockIdx.y;
    const long tile_m = (long)blockIdx.x * 64;

    const int arow  = tid >> 3;
    const int acol  = (tid & 7) * 4;
    const float* pS = S + ((long)bz * 2048 + tile_m + arow) * 2048 + acol;
    const int aoff  = arow * 32 + acol;
    const float m_r = Mrow[bz * 2048 + tile_m + arow];

    const short* pB = encT + (long)bz * 512 * 2048
                    + (long)(wave * 64 + l16) * 2048 + quad * 8;

    f32x4 acc[4][4] = {};
    short8 bfr[2][4];
    f32x4 sp[2];

    {
        f32x4 s0 = *(const f32x4*)pS;
        short4v h;
#pragma unroll
        for (int e = 0; e < 4; e++) h[e] = f2bf(__expf(s0[e] - m_r));
        *(short4v*)(As + aoff) = h;
    }
    sp[1] = *(const f32x4*)(pS + 32);
#pragma unroll
    for (int j = 0; j < 4; j++)
        bfr[0][j] = *(const short8*)(pB + (long)j * 16 * 2048);

    auto step = [&](int k0, int p) {
        __syncthreads();
        const bool more  = (k0 + 32 < 2048);
        const bool more2 = (k0 + 64 < 2048);
        if (more2) sp[p] = *(const f32x4*)(pS + k0 + 64);
        if (more) {
#pragma unroll
            for (int j = 0; j < 4; j++)
                bfr[p ^ 1][j] = *(const short8*)(pB + (long)j * 16 * 2048 + k0 + 32);
        }
        short8 a[4];
#pragma unroll
        for (int i = 0; i < 4; i++)
            a[i] = *(const short8*)&As[p * 2048 + (i * 16 + l16) * 32 + quad * 8];
#pragma unroll
        for (int i = 0; i < 4; i++)
#pragma unroll
            for (int j = 0; j < 4; j++)
                acc[i][j] = __builtin_amdgcn_mfma_f32_16x16x32_bf16(a[i], bfr[p][j], acc[i][j], 0, 0, 0);
        if (more) {
            f32x4 sv = sp[p ^ 1];
            short4v h;
#pragma unroll
            for (int e = 0; e < 4; e++) h[e] = f2bf(__expf(sv[e] - m_r));
            *(short4v*)(As + (p ^ 1) * 2048 + aoff) = h;
        }
    };

    for (int k0 = 0; k0 < 2048; k0 += 64) {
        step(k0, 0);
        step(k0 + 32, 1);
    }

    float li[4][4];
#pragma unroll
    for (int i = 0; i < 4; i++)
#pragma unroll
        for (int r = 0; r < 4; r++)
            li[i][r] = Linv[bz * 2048 + tile_m + i * 16 + quad * 4 + r];
#pragma unroll
    for (int i = 0; i < 4; i++)
#pragma unroll
        for (int j = 0; j < 4; j++) {
            const long row0 = tile_m + i * 16 + quad * 4;
            const long col  = wave * 64 + j * 16 + l16;
#pragma unroll
            for (int r = 0; r < 4; r++)
                Out[((long)bz * 2048 + row0 + r) * 512 + col] = acc[i][j][r] * li[i][r];
        }
}

// ---------------------------------------------------------------------------
extern "C" void kernel_launch(void* const* d_in, const int* in_sizes, int n_in,
                              void* d_out, int out_size, void* d_ws, size_t ws_size,
                              hipStream_t stream)
{
    const float* enc = (const float*)d_in[0];   // [8,2048,512]
    const float* dec = (const float*)d_in[1];   // [8,2048,512]
    const float* W   = (const float*)d_in[2];   // [512,512]
    float* out = (float*)d_out;                 // [8,2048,512]

    const long BSE = 8l * 2048 * 512;
    const long NW  = 512l * 512;

    char* p = (char*)d_ws;
    auto take = [&](long bytes) { char* r = p; p += (bytes + 255) & ~255l; return r; };
    short* enc_hi = (short*)take(BSE * 2);
    short* enc_lo = (short*)take(BSE * 2);
    short* dec_hi = (short*)take(BSE * 2);
    short* dec_lo = (short*)take(BSE * 2);
    short* ep_hi  = (short*)take(BSE * 2);
    short* ep_lo  = (short*)take(BSE * 2);
    short* enc_t  = (short*)take(BSE * 2);
    short* wt_hi  = (short*)take(NW * 2);
    short* wt_lo  = (short*)take(NW * 2);
    float* logits = (float*)take(8l * 2048 * 2048 * 4);
    float2* stats = (float2*)enc_lo;                       // dead after enc_proj
    float*  MrowA = (float*)(enc_lo + 4l * 1024 * 1024);
    float*  LinvA = (float*)(enc_lo + 5l * 1024 * 1024);
    (void)ws_size; (void)in_sizes; (void)n_in; (void)out_size;

    encprep_kernel<<<dim3(64, 16, 8), 256, 0, stream>>>(enc, enc_hi, enc_lo, enc_t);
    split_kernel<<<4096, 256, 0, stream>>>(dec, dec_hi, dec_lo);
    split_w_kernel<<<1024, 256, 0, stream>>>(W, wt_hi, wt_lo);

    // enc_proj = enc @ W  (M=16384, N=512, K=512), 3-term, split bf16 out
    // -- 32x32x16 probe kernel
    gemm_bt32_split<<<dim3(4, 128, 1), 256, 32 * 1024, stream>>>(
        enc_hi, enc_lo, wt_hi, wt_lo, ep_hi, ep_lo,
        512, 512, 512, 512);

    // logits[b] = dec[b] @ ep[b]^T  (M=2048, N=2048, K=512) x 8, 3-term + stats
    gemm_bt<3, false, true><<<dim3(16, 16, 8), 256, 64 * 1024 + 1024, stream>>>(
        dec_hi, dec_lo, ep_hi, ep_lo, logits, nullptr, nullptr, stats,
        512, 512, 512, 2048, 2048l * 512, 2048l * 512, 2048l * 2048);

    combine_kernel<<<64, 256, 0, stream>>>(stats, MrowA, LinvA);

    // out[b] = softmax(S[b]) @ enc[b]  (fused exp; 64q x 512e blocks) x 8
    pv_wide<<<dim3(32, 8), 512, 8 * 1024, stream>>>(
        logits, enc_t, MrowA, LinvA, out);
}